// Round 2
// baseline (363.507 us; speedup 1.0000x reference)
//
#include <hip/hip_runtime.h>
#include <hip/hip_bf16.h>

// Problem constants (from setup_inputs): B=2, S=2048, DIN=2048, DOUT=8192
#define M_DIM 4096   // B*S
#define K_DIM 2048   // DIN
#define N_DIM 8192   // DOUT

#define BM 128
#define BN 128
#define BK 32

typedef __bf16 bf16x8 __attribute__((ext_vector_type(8)));
typedef __bf16 bf16x4 __attribute__((ext_vector_type(4)));
typedef float  f32x4  __attribute__((ext_vector_type(4)));

// ---------------- prep kernels ----------------

// x: fp32 [M,K] -> xc = clip(round(x/s), -z, 255-z)  (exact small int in bf16)
__global__ void prep_x_kernel(const float4* __restrict__ x, __bf16* __restrict__ xc,
                              const float* __restrict__ a_scale, const int* __restrict__ a_zp,
                              int nquads) {
    const float s  = a_scale[0];
    const float z  = (float)a_zp[0];
    const float lo = -z, hi = 255.0f - z;
    int idx    = blockIdx.x * blockDim.x + threadIdx.x;
    int stride = gridDim.x * blockDim.x;
    for (; idx < nquads; idx += stride) {
        float4 v = x[idx];
        float q0 = fminf(fmaxf(roundf(v.x / s), lo), hi);
        float q1 = fminf(fmaxf(roundf(v.y / s), lo), hi);
        float q2 = fminf(fmaxf(roundf(v.z / s), lo), hi);
        float q3 = fminf(fmaxf(roundf(v.w / s), lo), hi);
        bf16x4 o = { (__bf16)q0, (__bf16)q1, (__bf16)q2, (__bf16)q3 };
        *reinterpret_cast<bf16x4*>(&xc[(size_t)idx * 4]) = o;
    }
}

// weight_q: int32 [N,K] (values 0..255) -> wc = (w_q - w_zp[o])  (exact small int in bf16)
__global__ void prep_w_kernel(const int4* __restrict__ wq, __bf16* __restrict__ wc,
                              const int* __restrict__ w_zp, int nquads) {
    int idx    = blockIdx.x * blockDim.x + threadIdx.x;
    int stride = gridDim.x * blockDim.x;
    for (; idx < nquads; idx += stride) {
        int4 v = wq[idx];
        int o = (idx * 4) >> 11;            // flat/2048: out-channel (4 elems share row; K%4==0)
        float zp = (float)w_zp[o];
        bf16x4 out = { (__bf16)((float)v.x - zp), (__bf16)((float)v.y - zp),
                       (__bf16)((float)v.z - zp), (__bf16)((float)v.w - zp) };
        *reinterpret_cast<bf16x4*>(&wc[(size_t)idx * 4]) = out;
    }
}

// ---------------- GEMM ----------------

__device__ __forceinline__ void glds16(const __bf16* g, __bf16* l) {
    __builtin_amdgcn_global_load_lds(
        (const __attribute__((address_space(1))) void*)g,
        (__attribute__((address_space(3))) void*)l,
        16, 0, 0);
}

// A: [M][K] bf16 (centered x), Bw: [N][K] bf16 (centered w).
// C[m,o] = a_s*w_scale[o]*sum_k A[m,k]*Bw[o,k] + bias[o]
__global__ __launch_bounds__(256) void gemm_kernel(
    const __bf16* __restrict__ A,
    const __bf16* __restrict__ Bw,
    const float* __restrict__ w_scale,
    const float* __restrict__ bias,
    const float* __restrict__ a_scale,
    float* __restrict__ C)
{
    __shared__ __bf16 As[BM * BK];   // [128][32], row-major, 8 KiB
    __shared__ __bf16 Bs[BN * BK];   // [128][32], 8 KiB

    const int tid  = threadIdx.x;
    const int lane = tid & 63;
    const int wave = tid >> 6;       // 4 waves
    const int wr   = wave >> 1;      // 0..1  (64-row half)
    const int wc   = wave & 1;       // 0..1  (64-col half)

    const int bn0 = blockIdx.x * BN;
    const int bm0 = blockIdx.y * BM;

    f32x4 acc[4][4];
    #pragma unroll
    for (int i = 0; i < 4; ++i)
        #pragma unroll
        for (int j = 0; j < 4; ++j)
            acc[i][j] = (f32x4){0.f, 0.f, 0.f, 0.f};

    // staging: tile is 128 rows x 32 cols bf16 = 8192 B = 512 chunks of 16 B.
    // chunk c -> row c>>2, col8 (c&3)*8 ; LDS linear offset = c*16 B (row-major match).
    const int c0 = tid, c1 = tid + 256;
    const int a_row0 = c0 >> 2, a_col0 = (c0 & 3) * 8;
    const int a_row1 = c1 >> 2, a_col1 = (c1 & 3) * 8;

    const __bf16* Abase = A  + (size_t)bm0 * K_DIM;
    const __bf16* Bbase = Bw + (size_t)bn0 * K_DIM;

    // fragment read coords (16x16x32 layout: row=lane&15, k = (lane>>4)*8 .. +8)
    const int fr = lane & 15;
    const int kg = (lane >> 4) * 8;

    for (int k0 = 0; k0 < K_DIM; k0 += BK) {
        __syncthreads();   // previous tile's ds_reads done before overwrite
        glds16(Abase + (size_t)a_row0 * K_DIM + k0 + a_col0, &As[c0 * 8]);
        glds16(Abase + (size_t)a_row1 * K_DIM + k0 + a_col1, &As[c1 * 8]);
        glds16(Bbase + (size_t)a_row0 * K_DIM + k0 + a_col0, &Bs[c0 * 8]);
        glds16(Bbase + (size_t)a_row1 * K_DIM + k0 + a_col1, &Bs[c1 * 8]);
        __syncthreads();   // compiler drains vmcnt(0) before s_barrier

        bf16x8 af[4], bfv[4];
        #pragma unroll
        for (int i = 0; i < 4; ++i) {
            int row = wr * 64 + i * 16 + fr;
            af[i] = *reinterpret_cast<const bf16x8*>(&As[row * BK + kg]);
        }
        #pragma unroll
        for (int j = 0; j < 4; ++j) {
            int row = wc * 64 + j * 16 + fr;
            bfv[j] = *reinterpret_cast<const bf16x8*>(&Bs[row * BK + kg]);
        }
        #pragma unroll
        for (int i = 0; i < 4; ++i)
            #pragma unroll
            for (int j = 0; j < 4; ++j)
                acc[i][j] = __builtin_amdgcn_mfma_f32_16x16x32_bf16(af[i], bfv[j], acc[i][j], 0, 0, 0);
    }

    // epilogue: C/D layout col=lane&15, row=(lane>>4)*4 + v   [m89-verified]
    const float a_s = a_scale[0];
    const int   fq  = lane >> 4;
    #pragma unroll
    for (int j = 0; j < 4; ++j) {
        int col = bn0 + wc * 64 + j * 16 + fr;
        float wsc = w_scale[col] * a_s;
        float bb  = bias[col];
        #pragma unroll
        for (int i = 0; i < 4; ++i) {
            int rowg = bm0 + wr * 64 + i * 16 + fq * 4;
            #pragma unroll
            for (int v = 0; v < 4; ++v) {
                C[(size_t)(rowg + v) * N_DIM + col] = wsc * acc[i][j][v] + bb;
            }
        }
    }
}

// ---------------- launch ----------------

extern "C" void kernel_launch(void* const* d_in, const int* in_sizes, int n_in,
                              void* d_out, int out_size, void* d_ws, size_t ws_size,
                              hipStream_t stream) {
    const float* x        = (const float*)d_in[0];
    const float* a_scale  = (const float*)d_in[1];
    const int*   a_zp     = (const int*)d_in[2];
    const int*   weight_q = (const int*)d_in[3];
    const float* w_scale  = (const float*)d_in[4];
    const int*   w_zp     = (const int*)d_in[5];
    const float* bias     = (const float*)d_in[6];
    float*       out      = (float*)d_out;

    __bf16* xc = (__bf16*)d_ws;                                        // 16.8 MB
    __bf16* wc = (__bf16*)((char*)d_ws + (size_t)M_DIM * K_DIM * 2);   // 33.6 MB

    prep_x_kernel<<<2048, 256, 0, stream>>>((const float4*)x, xc, a_scale, a_zp,
                                            (M_DIM * K_DIM) / 4);
    prep_w_kernel<<<2048, 256, 0, stream>>>((const int4*)weight_q, wc, w_zp,
                                            (N_DIM * K_DIM) / 4);

    dim3 grid(N_DIM / BN, M_DIM / BM);   // (64, 32) = 2048 blocks
    gemm_kernel<<<grid, 256, 0, stream>>>(xc, wc, w_scale, bias, a_scale, out);
}

// Round 3
// 292.682 us; speedup vs baseline: 1.2420x; 1.2420x over previous
//
#include <hip/hip_runtime.h>
#include <hip/hip_bf16.h>

// Problem constants: B=2, S=2048, DIN=2048, DOUT=8192
#define M_DIM 4096
#define K_DIM 2048
#define N_DIM 8192

#define BM 128
#define BN 128
#define BK 64          // K elements per tile (1 byte each)

typedef int   int32x4 __attribute__((ext_vector_type(4)));
typedef float f32x4   __attribute__((ext_vector_type(4)));

// ---------------- workspace layout (bytes) ----------------
// xc  int8 [M][K]   @ 0          (8.4 MB)
// wc  int8 [N][K]   @ 8388608    (16.8 MB)
// rx  int32[M]      @ 25165824
// al  int32[N]      @ 25182208
// g   f32  [N]      @ 25214976
// F0  f32  [N]      @ 25247744
#define XC_OFF 0
#define WC_OFF 8388608UL
#define RX_OFF 25165824UL
#define AL_OFF 25182208UL
#define G_OFF  25214976UL
#define F0_OFF 25247744UL

__device__ __forceinline__ int pack4(int a, int b, int c, int d) {
    return (a & 255) | ((b & 255) << 8) | ((c & 255) << 16) | ((d & 255) << 24);
}

// ---------------- prep: x -> x' = clip(round(x/s)+z,0,255)-128, plus row-sum rx ----------------
__global__ __launch_bounds__(256) void prep_x_kernel(
    const float4* __restrict__ x, signed char* __restrict__ xc, int* __restrict__ rx,
    const float* __restrict__ a_scale, const int* __restrict__ a_zp)
{
    const int row = blockIdx.x;            // 4096 rows
    const int tid = threadIdx.x;           // 256 threads, 8 elems each
    const float s = a_scale[0];
    const float z = (float)a_zp[0];
    int sum = 0;
    int* xci = (int*)(xc + (size_t)row * K_DIM);
    const float4* xr = x + (size_t)row * (K_DIM / 4);
    #pragma unroll
    for (int it = 0; it < 2; ++it) {
        int qi = tid + it * 256;           // float4 index within row (0..511)
        float4 v = xr[qi];
        int q0 = (int)(fminf(fmaxf(roundf(v.x / s) + z, 0.f), 255.f)) - 128;
        int q1 = (int)(fminf(fmaxf(roundf(v.y / s) + z, 0.f), 255.f)) - 128;
        int q2 = (int)(fminf(fmaxf(roundf(v.z / s) + z, 0.f), 255.f)) - 128;
        int q3 = (int)(fminf(fmaxf(roundf(v.w / s) + z, 0.f), 255.f)) - 128;
        sum += q0 + q1 + q2 + q3;
        xci[qi] = pack4(q0, q1, q2, q3);
    }
    // reduce sum over block
    #pragma unroll
    for (int off = 32; off > 0; off >>= 1) sum += __shfl_down(sum, off);
    __shared__ int wsum[4];
    if ((tid & 63) == 0) wsum[tid >> 6] = sum;
    __syncthreads();
    if (tid == 0) rx[row] = wsum[0] + wsum[1] + wsum[2] + wsum[3];
}

// ---------------- prep: w -> w' = w_q-128, plus per-channel alpha/g/F0 ----------------
__global__ __launch_bounds__(256) void prep_w_kernel(
    const int4* __restrict__ wq, signed char* __restrict__ wc,
    int* __restrict__ al, float* __restrict__ g, float* __restrict__ F0,
    const float* __restrict__ a_scale, const int* __restrict__ a_zp,
    const float* __restrict__ w_scale, const int* __restrict__ w_zp,
    const float* __restrict__ bias)
{
    const int o   = blockIdx.x;            // 8192 out-channels
    const int tid = threadIdx.x;
    int sum = 0;
    int* wci = (int*)(wc + (size_t)o * K_DIM);
    const int4* wr = wq + (size_t)o * (K_DIM / 4);
    #pragma unroll
    for (int it = 0; it < 2; ++it) {
        int qi = tid + it * 256;
        int4 v = wr[qi];
        int q0 = v.x - 128, q1 = v.y - 128, q2 = v.z - 128, q3 = v.w - 128;
        sum += q0 + q1 + q2 + q3;
        wci[qi] = pack4(q0, q1, q2, q3);
    }
    #pragma unroll
    for (int off = 32; off > 0; off >>= 1) sum += __shfl_down(sum, off);
    __shared__ int wsum[4];
    if ((tid & 63) == 0) wsum[tid >> 6] = sum;
    __syncthreads();
    if (tid == 0) {
        int rw    = wsum[0] + wsum[1] + wsum[2] + wsum[3];
        int alpha = 128 - w_zp[o];
        int beta  = 128 - a_zp[0];
        // C0 = beta*(rw + K*alpha)  (exact in int32: |beta|<=28, |rw + K*alpha| <= 3.2e5)
        int C0    = beta * (rw + K_DIM * alpha);
        float gg  = a_scale[0] * w_scale[o];
        al[o] = alpha;
        g[o]  = gg;
        F0[o] = gg * (float)C0 + bias[o];
    }
}

// ---------------- GEMM (i8, m97 structure) ----------------

__device__ __forceinline__ void glds16(const void* gptr, void* lptr) {
    __builtin_amdgcn_global_load_lds(
        (const __attribute__((address_space(1))) void*)gptr,
        (__attribute__((address_space(3))) void*)lptr,
        16, 0, 0);
}

// out[m,o] = g[o]*float(sum_k x'[m,k]*w'[o,k] + al[o]*rx[m]) + F0[o]
__global__ __launch_bounds__(256) void gemm_i8_kernel(
    const signed char* __restrict__ A,
    const signed char* __restrict__ Bw,
    const int*   __restrict__ rx,
    const int*   __restrict__ al,
    const float* __restrict__ g,
    const float* __restrict__ F0,
    float* __restrict__ C)
{
    __shared__ __align__(16) signed char As[BM * BK];   // 8 KiB
    __shared__ __align__(16) signed char Bs[BN * BK];   // 8 KiB

    const int tid  = threadIdx.x;
    const int lane = tid & 63;
    const int wave = tid >> 6;
    const int wr   = wave >> 1;        // 0..1
    const int wc   = wave & 1;         // 0..1

    const int bn0 = blockIdx.x * BN;
    const int bm0 = blockIdx.y * BM;

    int32x4 acc[4][4];
    #pragma unroll
    for (int i = 0; i < 4; ++i)
        #pragma unroll
        for (int j = 0; j < 4; ++j)
            acc[i][j] = (int32x4){0, 0, 0, 0};

    // staging: tile 128 rows x 64 B = 8192 B = 512 chunks of 16 B
    // chunk c -> row c>>2, colByte (c&3)*16; LDS linear at c*16 (row-major match)
    const int c0 = tid, c1 = tid + 256;
    const int r0 = c0 >> 2, cb0 = (c0 & 3) * 16;
    const int r1 = c1 >> 2, cb1 = (c1 & 3) * 16;

    const signed char* Abase = A  + (size_t)bm0 * K_DIM;
    const signed char* Bbase = Bw + (size_t)bn0 * K_DIM;

    const int fr = lane & 15;          // fragment row/col
    const int kg = (lane >> 4) * 16;   // byte offset of this lane's 16-byte K-slice

    for (int k0 = 0; k0 < K_DIM; k0 += BK) {
        __syncthreads();
        glds16(Abase + (size_t)r0 * K_DIM + k0 + cb0, &As[c0 * 16]);
        glds16(Abase + (size_t)r1 * K_DIM + k0 + cb1, &As[c1 * 16]);
        glds16(Bbase + (size_t)r0 * K_DIM + k0 + cb0, &Bs[c0 * 16]);
        glds16(Bbase + (size_t)r1 * K_DIM + k0 + cb1, &Bs[c1 * 16]);
        __syncthreads();

        int32x4 af[4], bf[4];
        #pragma unroll
        for (int i = 0; i < 4; ++i) {
            int row = wr * 64 + i * 16 + fr;
            af[i] = *reinterpret_cast<const int32x4*>(&As[row * BK + kg]);
        }
        #pragma unroll
        for (int j = 0; j < 4; ++j) {
            int row = wc * 64 + j * 16 + fr;
            bf[j] = *reinterpret_cast<const int32x4*>(&Bs[row * BK + kg]);
        }
        #pragma unroll
        for (int i = 0; i < 4; ++i)
            #pragma unroll
            for (int j = 0; j < 4; ++j)
                acc[i][j] = __builtin_amdgcn_mfma_i32_16x16x64_i8(af[i], bf[j], acc[i][j], 0, 0, 0);
    }

    // epilogue: C/D layout col=lane&15, row=(lane>>4)*4+v  (dtype-independent, m121-m128)
    const int fq = lane >> 4;
    int rxl[4][4];
    #pragma unroll
    for (int i = 0; i < 4; ++i)
        #pragma unroll
        for (int v = 0; v < 4; ++v)
            rxl[i][v] = rx[bm0 + wr * 64 + i * 16 + fq * 4 + v];

    #pragma unroll
    for (int j = 0; j < 4; ++j) {
        int col = bn0 + wc * 64 + j * 16 + fr;
        int   av = al[col];
        float gv = g[col];
        float fv = F0[col];
        #pragma unroll
        for (int i = 0; i < 4; ++i) {
            int rowg = bm0 + wr * 64 + i * 16 + fq * 4;
            #pragma unroll
            for (int v = 0; v < 4; ++v) {
                int t = acc[i][j][v] + av * rxl[i][v];
                C[(size_t)(rowg + v) * N_DIM + col] = fmaf(gv, (float)t, fv);
            }
        }
    }
}

// ---------------- launch ----------------

extern "C" void kernel_launch(void* const* d_in, const int* in_sizes, int n_in,
                              void* d_out, int out_size, void* d_ws, size_t ws_size,
                              hipStream_t stream) {
    const float* x        = (const float*)d_in[0];
    const float* a_scale  = (const float*)d_in[1];
    const int*   a_zp     = (const int*)d_in[2];
    const int*   weight_q = (const int*)d_in[3];
    const float* w_scale  = (const float*)d_in[4];
    const int*   w_zp     = (const int*)d_in[5];
    const float* bias     = (const float*)d_in[6];
    float*       out      = (float*)d_out;

    char* ws = (char*)d_ws;
    signed char* xc = (signed char*)(ws + XC_OFF);
    signed char* wc = (signed char*)(ws + WC_OFF);
    int*   rx = (int*)(ws + RX_OFF);
    int*   al = (int*)(ws + AL_OFF);
    float* g  = (float*)(ws + G_OFF);
    float* F0 = (float*)(ws + F0_OFF);

    prep_x_kernel<<<M_DIM, 256, 0, stream>>>((const float4*)x, xc, rx, a_scale, a_zp);
    prep_w_kernel<<<N_DIM, 256, 0, stream>>>((const int4*)weight_q, wc, al, g, F0,
                                             a_scale, a_zp, w_scale, w_zp, bias);

    dim3 grid(N_DIM / BN, M_DIM / BM);   // (64, 32)
    gemm_i8_kernel<<<grid, 256, 0, stream>>>(xc, wc, rx, al, g, F0, out);
}

// Round 4
// 292.083 us; speedup vs baseline: 1.2445x; 1.0021x over previous
//
#include <hip/hip_runtime.h>
#include <hip/hip_bf16.h>

// Problem constants: B=2, S=2048, DIN=2048, DOUT=8192
#define M_DIM 4096
#define K_DIM 2048
#define N_DIM 8192

#define NT 32          // K-tiles of 64 bytes each (K_DIM/64)

typedef int   int32x4  __attribute__((ext_vector_type(4)));
typedef int   int32x16 __attribute__((ext_vector_type(16)));

// ---------------- workspace layout (bytes) ----------------
#define XC_OFF 0
#define WC_OFF 8388608UL
#define RX_OFF 25165824UL
#define AL_OFF 25182208UL
#define G_OFF  25214976UL
#define F0_OFF 25247744UL

__device__ __forceinline__ int pack4(int a, int b, int c, int d) {
    return (a & 255) | ((b & 255) << 8) | ((c & 255) << 16) | ((d & 255) << 24);
}

// ---------------- prep: x -> x' = clip(round(x/s)+z,0,255)-128, plus row-sum rx ----------------
__global__ __launch_bounds__(256) void prep_x_kernel(
    const float4* __restrict__ x, signed char* __restrict__ xc, int* __restrict__ rx,
    const float* __restrict__ a_scale, const int* __restrict__ a_zp)
{
    const int row = blockIdx.x;            // 4096 rows
    const int tid = threadIdx.x;
    const float s = a_scale[0];
    const float z = (float)a_zp[0];
    int sum = 0;
    int* xci = (int*)(xc + (size_t)row * K_DIM);
    const float4* xr = x + (size_t)row * (K_DIM / 4);
    #pragma unroll
    for (int it = 0; it < 2; ++it) {
        int qi = tid + it * 256;
        float4 v = xr[qi];
        int q0 = (int)(fminf(fmaxf(roundf(v.x / s) + z, 0.f), 255.f)) - 128;
        int q1 = (int)(fminf(fmaxf(roundf(v.y / s) + z, 0.f), 255.f)) - 128;
        int q2 = (int)(fminf(fmaxf(roundf(v.z / s) + z, 0.f), 255.f)) - 128;
        int q3 = (int)(fminf(fmaxf(roundf(v.w / s) + z, 0.f), 255.f)) - 128;
        sum += q0 + q1 + q2 + q3;
        xci[qi] = pack4(q0, q1, q2, q3);
    }
    #pragma unroll
    for (int off = 32; off > 0; off >>= 1) sum += __shfl_down(sum, off);
    __shared__ int wsum[4];
    if ((tid & 63) == 0) wsum[tid >> 6] = sum;
    __syncthreads();
    if (tid == 0) rx[row] = wsum[0] + wsum[1] + wsum[2] + wsum[3];
}

// ---------------- prep: w -> w' = w_q-128, plus per-channel alpha/g/F0 ----------------
__global__ __launch_bounds__(256) void prep_w_kernel(
    const int4* __restrict__ wq, signed char* __restrict__ wc,
    int* __restrict__ al, float* __restrict__ g, float* __restrict__ F0,
    const float* __restrict__ a_scale, const int* __restrict__ a_zp,
    const float* __restrict__ w_scale, const int* __restrict__ w_zp,
    const float* __restrict__ bias)
{
    const int o   = blockIdx.x;
    const int tid = threadIdx.x;
    int sum = 0;
    int* wci = (int*)(wc + (size_t)o * K_DIM);
    const int4* wr = wq + (size_t)o * (K_DIM / 4);
    #pragma unroll
    for (int it = 0; it < 2; ++it) {
        int qi = tid + it * 256;
        int4 v = wr[qi];
        int q0 = v.x - 128, q1 = v.y - 128, q2 = v.z - 128, q3 = v.w - 128;
        sum += q0 + q1 + q2 + q3;
        wci[qi] = pack4(q0, q1, q2, q3);
    }
    #pragma unroll
    for (int off = 32; off > 0; off >>= 1) sum += __shfl_down(sum, off);
    __shared__ int wsum[4];
    if ((tid & 63) == 0) wsum[tid >> 6] = sum;
    __syncthreads();
    if (tid == 0) {
        int rw    = wsum[0] + wsum[1] + wsum[2] + wsum[3];
        int alpha = 128 - w_zp[o];
        int beta  = 128 - a_zp[0];
        int C0    = beta * (rw + K_DIM * alpha);
        float gg  = a_scale[0] * w_scale[o];
        al[o] = alpha;
        g[o]  = gg;
        F0[o] = gg * (float)C0 + bias[o];
    }
}

// ---------------- GEMM: 256x256 tile, BK=64B, 4 LDS buffers, counted vmcnt ----------------

__device__ __forceinline__ void glds16(const void* gptr, void* lptr) {
    __builtin_amdgcn_global_load_lds(
        (const __attribute__((address_space(1))) void*)gptr,
        (__attribute__((address_space(3))) void*)lptr, 16, 0, 0);
}

// out[m,o] = g[o]*float(sum_k x'[m,k]*w'[o,k] + al[o]*rx[m]) + F0[o]
__global__ __launch_bounds__(512) void gemm_i8_kernel(
    const signed char* __restrict__ A,
    const signed char* __restrict__ Bw,
    const int*   __restrict__ rx,
    const int*   __restrict__ al,
    const float* __restrict__ g,
    const float* __restrict__ F0,
    float* __restrict__ C)
{
    extern __shared__ signed char lds[];     // 131072 B: A bufs [0,64K), B bufs [64K,128K)
    signed char* ldsA = lds;
    signed char* ldsB = lds + 65536;

    const int tid  = threadIdx.x;
    const int lane = tid & 63;
    const int wave = tid >> 6;      // 8 waves
    const int wr   = wave >> 2;     // 0..1  (M)
    const int wc   = wave & 3;      // 0..3  (N)
    const int l31  = lane & 31;
    const int lk   = lane >> 5;     // 0..1
    const int rsw  = (l31 >> 1) & 3;

    // bijective XCD swizzle over 512 blocks (512 % 8 == 0)
    const int bid = blockIdx.x;
    const int swz = (bid & 7) * 64 + (bid >> 3);
    const int bn0 = (swz & 31) * 256;       // 32 n-tiles
    const int bm0 = (swz >> 5) * 256;       // 16 m-tiles

    // ---- staging: tile = 256 rows x 64 B = 16 KB = 1024 chunks of 16 B ----
    // LDS chunk c = r*4 + pc' holds global 16B-pair pc = pc' ^ ((r>>1)&3)  (inverse-swizzled source)
    const int  sr  = tid >> 2;                       // 0..127 (chunk2 adds +128, same swizzle)
    const int  spc = (tid & 3) ^ ((sr >> 1) & 3);
    const signed char* srcA0 = A  + (size_t)(bm0 + sr) * K_DIM + spc * 16;
    const signed char* srcA1 = srcA0 + (size_t)128 * K_DIM;
    const signed char* srcB0 = Bw + (size_t)(bn0 + sr) * K_DIM + spc * 16;
    const signed char* srcB1 = srcB0 + (size_t)128 * K_DIM;
    signed char* dstA0 = ldsA + tid * 16;
    signed char* dstB0 = ldsB + tid * 16;

#define STAGE_A(s) { const int kof = (s) * 64; const int bo = ((s) & 3) * 16384; \
    glds16(srcA0 + kof, dstA0 + bo); glds16(srcA1 + kof, dstA0 + bo + 8192); }
#define STAGE_B(s) { const int kof = (s) * 64; const int bo = ((s) & 3) * 16384; \
    glds16(srcB0 + kof, dstB0 + bo); glds16(srcB1 + kof, dstB0 + bo + 8192); }

    // ---- fragment read addressing (32x32x32: lane row = l31, 16B k-slice = pair ks*2+lk) ----
    int arowb[4], browb[2];
    #pragma unroll
    for (int im = 0; im < 4; ++im) arowb[im] = (wr * 128 + im * 32 + l31) * 64;
    #pragma unroll
    for (int jn = 0; jn < 2; ++jn) browb[jn] = (wc * 64 + jn * 32 + l31) * 64;
    const int aoff0 = ((0 + lk) ^ rsw) << 4;   // ks=0
    const int aoff1 = ((2 + lk) ^ rsw) << 4;   // ks=1

    int32x16 acc[4][2];
    #pragma unroll
    for (int im = 0; im < 4; ++im)
        #pragma unroll
        for (int jn = 0; jn < 2; ++jn)
            acc[im][jn] = (int32x16)(0);

#define TILE_PH(T, AOFF, STAGE_STMT) { \
    const int bo_ = ((T) & 3) * 16384; \
    int32x4 af[4], bf[2]; \
    _Pragma("unroll") for (int im = 0; im < 4; ++im) \
        af[im] = *(const int32x4*)(ldsA + bo_ + arowb[im] + (AOFF)); \
    _Pragma("unroll") for (int jn = 0; jn < 2; ++jn) \
        bf[jn] = *(const int32x4*)(ldsB + bo_ + browb[jn] + (AOFF)); \
    STAGE_STMT; \
    __builtin_amdgcn_s_barrier(); \
    __builtin_amdgcn_s_setprio(1); \
    _Pragma("unroll") for (int im = 0; im < 4; ++im) \
        _Pragma("unroll") for (int jn = 0; jn < 2; ++jn) \
            acc[im][jn] = __builtin_amdgcn_mfma_i32_32x32x32_i8(af[im], bf[jn], acc[im][jn], 0, 0, 0); \
    __builtin_amdgcn_s_setprio(0); \
}

#define MIDBAR __builtin_amdgcn_s_barrier();
#define BOUND(N) { asm volatile("s_waitcnt vmcnt(" #N ")" ::: "memory"); __builtin_amdgcn_s_barrier(); }

    // prologue: stage tiles 0,1,2 (12 loads/wave); wait to 8 -> tile 0 resident
    STAGE_A(0); STAGE_B(0);
    STAGE_A(1); STAGE_B(1);
    STAGE_A(2); STAGE_B(2);
    asm volatile("s_waitcnt vmcnt(8)" ::: "memory");
    __builtin_amdgcn_s_barrier();

    // main loop: during tile t stage tile t+3 (always a buffer nobody reads);
    // boundary vmcnt(8) keeps 2 tiles (8 loads) in flight across every barrier.
    #pragma unroll 1
    for (int t = 0; t < 29; ++t) {
        TILE_PH(t, aoff0, STAGE_A(t + 3)); MIDBAR;
        TILE_PH(t, aoff1, STAGE_B(t + 3));
        BOUND(8);
    }
    TILE_PH(29, aoff0, ((void)0)); MIDBAR;
    TILE_PH(29, aoff1, ((void)0)); BOUND(4);
    TILE_PH(30, aoff0, ((void)0)); MIDBAR;
    TILE_PH(30, aoff1, ((void)0)); BOUND(0);
    TILE_PH(31, aoff0, ((void)0)); MIDBAR;
    TILE_PH(31, aoff1, ((void)0));

    // ---- epilogue: 32x32 C/D layout col=lane&31, row=(r&3)+8*(r>>2)+4*(lane>>5) ----
    #pragma unroll
    for (int im = 0; im < 4; ++im) {
        int rxv[16];
        #pragma unroll
        for (int r = 0; r < 16; ++r)
            rxv[r] = rx[bm0 + wr * 128 + im * 32 + (r & 3) + 8 * (r >> 2) + 4 * lk];
        #pragma unroll
        for (int jn = 0; jn < 2; ++jn) {
            const int col = bn0 + wc * 64 + jn * 32 + l31;
            const float gg = g[col];
            const float ff = F0[col];
            const int   aa = al[col];
            #pragma unroll
            for (int r = 0; r < 16; ++r) {
                const int grow = bm0 + wr * 128 + im * 32 + (r & 3) + 8 * (r >> 2) + 4 * lk;
                const int tv = acc[im][jn][r] + aa * rxv[r];
                C[(size_t)grow * N_DIM + col] = fmaf(gg, (float)tv, ff);
            }
        }
    }
#undef TILE_PH
#undef STAGE_A
#undef STAGE_B
#undef MIDBAR
#undef BOUND
}

// ---------------- launch ----------------

extern "C" void kernel_launch(void* const* d_in, const int* in_sizes, int n_in,
                              void* d_out, int out_size, void* d_ws, size_t ws_size,
                              hipStream_t stream) {
    const float* x        = (const float*)d_in[0];
    const float* a_scale  = (const float*)d_in[1];
    const int*   a_zp     = (const int*)d_in[2];
    const int*   weight_q = (const int*)d_in[3];
    const float* w_scale  = (const float*)d_in[4];
    const int*   w_zp     = (const int*)d_in[5];
    const float* bias     = (const float*)d_in[6];
    float*       out      = (float*)d_out;

    char* ws = (char*)d_ws;
    signed char* xc = (signed char*)(ws + XC_OFF);
    signed char* wc = (signed char*)(ws + WC_OFF);
    int*   rx = (int*)(ws + RX_OFF);
    int*   al = (int*)(ws + AL_OFF);
    float* g  = (float*)(ws + G_OFF);
    float* F0 = (float*)(ws + F0_OFF);

    prep_x_kernel<<<M_DIM, 256, 0, stream>>>((const float4*)x, xc, rx, a_scale, a_zp);
    prep_w_kernel<<<N_DIM, 256, 0, stream>>>((const int4*)weight_q, wc, al, g, F0,
                                             a_scale, a_zp, w_scale, w_zp, bias);

    gemm_i8_kernel<<<512, 512, 131072, stream>>>(xc, wc, rx, al, g, F0, out);
}

// Round 5
// 288.851 us; speedup vs baseline: 1.2585x; 1.0112x over previous
//
#include <hip/hip_runtime.h>
#include <hip/hip_bf16.h>

// Problem constants: B=2, S=2048, DIN=2048, DOUT=8192
#define M_DIM 4096
#define K_DIM 2048
#define N_DIM 8192

typedef int   int32x4  __attribute__((ext_vector_type(4)));
typedef int   int32x16 __attribute__((ext_vector_type(16)));

// ---------------- workspace layout (bytes) ----------------
#define XC_OFF 0
#define WC_OFF 8388608UL
#define RX_OFF 25165824UL
#define AL_OFF 25182208UL
#define G_OFF  25214976UL
#define F0_OFF 25247744UL

__device__ __forceinline__ int pack4(int a, int b, int c, int d) {
    return (a & 255) | ((b & 255) << 8) | ((c & 255) << 16) | ((d & 255) << 24);
}

// ---------------- prep: x -> x' = clip(round(x/s)+z,0,255)-128, plus row-sum rx ----------------
__global__ __launch_bounds__(256) void prep_x_kernel(
    const float4* __restrict__ x, signed char* __restrict__ xc, int* __restrict__ rx,
    const float* __restrict__ a_scale, const int* __restrict__ a_zp)
{
    const int row = blockIdx.x;
    const int tid = threadIdx.x;
    const float s = a_scale[0];
    const float z = (float)a_zp[0];
    int sum = 0;
    int* xci = (int*)(xc + (size_t)row * K_DIM);
    const float4* xr = x + (size_t)row * (K_DIM / 4);
    #pragma unroll
    for (int it = 0; it < 2; ++it) {
        int qi = tid + it * 256;
        float4 v = xr[qi];
        int q0 = (int)(fminf(fmaxf(roundf(v.x / s) + z, 0.f), 255.f)) - 128;
        int q1 = (int)(fminf(fmaxf(roundf(v.y / s) + z, 0.f), 255.f)) - 128;
        int q2 = (int)(fminf(fmaxf(roundf(v.z / s) + z, 0.f), 255.f)) - 128;
        int q3 = (int)(fminf(fmaxf(roundf(v.w / s) + z, 0.f), 255.f)) - 128;
        sum += q0 + q1 + q2 + q3;
        xci[qi] = pack4(q0, q1, q2, q3);
    }
    #pragma unroll
    for (int off = 32; off > 0; off >>= 1) sum += __shfl_down(sum, off);
    __shared__ int wsum[4];
    if ((tid & 63) == 0) wsum[tid >> 6] = sum;
    __syncthreads();
    if (tid == 0) rx[row] = wsum[0] + wsum[1] + wsum[2] + wsum[3];
}

// ---------------- prep: w -> w' = w_q-128, plus per-channel alpha/g/F0 ----------------
__global__ __launch_bounds__(256) void prep_w_kernel(
    const int4* __restrict__ wq, signed char* __restrict__ wc,
    int* __restrict__ al, float* __restrict__ g, float* __restrict__ F0,
    const float* __restrict__ a_scale, const int* __restrict__ a_zp,
    const float* __restrict__ w_scale, const int* __restrict__ w_zp,
    const float* __restrict__ bias)
{
    const int o   = blockIdx.x;
    const int tid = threadIdx.x;
    int sum = 0;
    int* wci = (int*)(wc + (size_t)o * K_DIM);
    const int4* wr = wq + (size_t)o * (K_DIM / 4);
    #pragma unroll
    for (int it = 0; it < 2; ++it) {
        int qi = tid + it * 256;
        int4 v = wr[qi];
        int q0 = v.x - 128, q1 = v.y - 128, q2 = v.z - 128, q3 = v.w - 128;
        sum += q0 + q1 + q2 + q3;
        wci[qi] = pack4(q0, q1, q2, q3);
    }
    #pragma unroll
    for (int off = 32; off > 0; off >>= 1) sum += __shfl_down(sum, off);
    __shared__ int wsum[4];
    if ((tid & 63) == 0) wsum[tid >> 6] = sum;
    __syncthreads();
    if (tid == 0) {
        int rw    = wsum[0] + wsum[1] + wsum[2] + wsum[3];
        int alpha = 128 - w_zp[o];
        int beta  = 128 - a_zp[0];
        int C0    = beta * (rw + K_DIM * alpha);
        float gg  = a_scale[0] * w_scale[o];
        al[o] = alpha;
        g[o]  = gg;
        F0[o] = gg * (float)C0 + bias[o];
    }
}

// ---------------- GEMM: 256x256 tile, BK=64B, 4 LDS buffers, paired-row XOR layout ----------------
// LDS tile buffer = [128 lds-rows][128 B]; lds-row r holds tile-rows {2r, 2r+1} (64 B each).
// 16B chunk c_lds at (r, c_lds) holds global chunk c_g = c_lds ^ (r&7)
//   (c_g>>2 = tile-row parity, c_g&3 = k-chunk). 128-B rows span all 32 banks ->
//   XOR across 8 chunks makes every af/bf ds_read_b128 hit all 8 bank-quads per 8 lanes.

__device__ __forceinline__ void glds16(const void* gptr, void* lptr) {
    __builtin_amdgcn_global_load_lds(
        (const __attribute__((address_space(1))) void*)gptr,
        (__attribute__((address_space(3))) void*)lptr, 16, 0, 0);
}

// out[m,o] = g[o]*float(sum_k x'[m,k]*w'[o,k] + al[o]*rx[m]) + F0[o]
__global__ __launch_bounds__(512) void gemm_i8_kernel(
    const signed char* __restrict__ A,
    const signed char* __restrict__ Bw,
    const int*   __restrict__ rx,
    const int*   __restrict__ al,
    const float* __restrict__ g,
    const float* __restrict__ F0,
    float* __restrict__ C)
{
    extern __shared__ signed char lds[];     // 131072 B: A bufs [0,64K), B bufs [64K,128K)
    signed char* ldsA = lds;
    signed char* ldsB = lds + 65536;

    const int tid  = threadIdx.x;
    const int lane = tid & 63;
    const int wave = tid >> 6;      // 8 waves
    const int wr   = wave >> 2;     // 0..1  (M)
    const int wc   = wave & 3;      // 0..3  (N)
    const int l31  = lane & 31;
    const int lk   = lane >> 5;     // 0..1

    // bijective XCD swizzle over 512 blocks (512 % 8 == 0)
    const int bid = blockIdx.x;
    const int swz = (bid & 7) * 64 + (bid >> 3);
    const int bn0 = (swz & 31) * 256;
    const int bm0 = (swz >> 5) * 256;

    // ---- staging: thread tid -> lds-row slr = tid>>3 (0..63), chunk c_lds = tid&7 ----
    // global chunk c_g = c_lds ^ (slr&7); second glds16 at +8192 B = lds-rows +64 = tile-rows +128
    const int slr = tid >> 3;
    const int cg  = (tid & 7) ^ (slr & 7);
    const int sp  = cg >> 2;        // tile-row parity
    const int skc = cg & 3;         // k-chunk (16 B)
    const signed char* srcA0 = A  + (size_t)(bm0 + 2 * slr + sp) * K_DIM + skc * 16;
    const signed char* srcA1 = srcA0 + (size_t)128 * K_DIM;
    const signed char* srcB0 = Bw + (size_t)(bn0 + 2 * slr + sp) * K_DIM + skc * 16;
    const signed char* srcB1 = srcB0 + (size_t)128 * K_DIM;
    signed char* dstA0 = ldsA + tid * 16;
    signed char* dstB0 = ldsB + tid * 16;

#define STAGE_A(s) { const int kof = (s) * 64; const int bo = ((s) & 3) * 16384; \
    glds16(srcA0 + kof, dstA0 + bo); glds16(srcA1 + kof, dstA0 + bo + 8192); }
#define STAGE_B(s) { const int kof = (s) * 64; const int bo = ((s) & 3) * 16384; \
    glds16(srcB0 + kof, dstB0 + bo); glds16(srcB1 + kof, dstB0 + bo + 8192); }

    // ---- fragment read addressing ----
    // tile-row tr = base + l31 -> lds-row r = base/2 + (l31>>1), parity pp = l31&1
    // chunk = (pp*4 + ph*2 + lk) ^ (r&7); r&7 = (l31>>1)&7 (bases are multiples of 16)
    const int q  = l31 >> 1;        // 0..15
    const int e  = q & 7;
    const int pp = l31 & 1;
    int arowb[4], browb[2];
    #pragma unroll
    for (int im = 0; im < 4; ++im) arowb[im] = (wr * 64 + im * 16 + q) * 128;
    #pragma unroll
    for (int jn = 0; jn < 2; ++jn) browb[jn] = (wc * 32 + jn * 16 + q) * 128;
    const int aoff0 = ((pp * 4 + lk) ^ e) * 16;   // ph=0 (k-chunk = lk)
    const int aoff1 = aoff0 ^ 32;                 // ph=1 (k-chunk = 2+lk)
    (void)aoff1;

    int32x16 acc[4][2];
    #pragma unroll
    for (int im = 0; im < 4; ++im)
        #pragma unroll
        for (int jn = 0; jn < 2; ++jn)
            acc[im][jn] = (int32x16)(0);

#define TILE_PH(T, AOFF, STAGE_STMT) { \
    const int bo_ = ((T) & 3) * 16384; \
    int32x4 af[4], bf[2]; \
    _Pragma("unroll") for (int im = 0; im < 4; ++im) \
        af[im] = *(const int32x4*)(ldsA + bo_ + arowb[im] + (AOFF)); \
    _Pragma("unroll") for (int jn = 0; jn < 2; ++jn) \
        bf[jn] = *(const int32x4*)(ldsB + bo_ + browb[jn] + (AOFF)); \
    STAGE_STMT; \
    __builtin_amdgcn_s_barrier(); \
    __builtin_amdgcn_s_setprio(1); \
    _Pragma("unroll") for (int im = 0; im < 4; ++im) \
        _Pragma("unroll") for (int jn = 0; jn < 2; ++jn) \
            acc[im][jn] = __builtin_amdgcn_mfma_i32_32x32x32_i8(af[im], bf[jn], acc[im][jn], 0, 0, 0); \
    __builtin_amdgcn_s_setprio(0); \
}

#define BOUND(N) { asm volatile("s_waitcnt vmcnt(" #N ")" ::: "memory"); __builtin_amdgcn_s_barrier(); }

    // prologue: stage tiles 0,1,2 (12 loads/thread); wait to 8 -> tile 0 resident
    STAGE_A(0); STAGE_B(0);
    STAGE_A(1); STAGE_B(1);
    STAGE_A(2); STAGE_B(2);
    asm volatile("s_waitcnt vmcnt(8)" ::: "memory");
    __builtin_amdgcn_s_barrier();

    // main loop: during tile t stage tile t+3 (buffer (t+3)&3 = (t-1)&3, whose reads
    // finished before the previous BOUND barrier); vmcnt(8) keeps 2 tiles in flight.
    #pragma unroll 1
    for (int t = 0; t < 29; ++t) {
        TILE_PH(t, aoff0, STAGE_A(t + 3));
        TILE_PH(t, aoff1, STAGE_B(t + 3));
        BOUND(8);
    }
    TILE_PH(29, aoff0, ((void)0));
    TILE_PH(29, aoff1, ((void)0)); BOUND(4);
    TILE_PH(30, aoff0, ((void)0));
    TILE_PH(30, aoff1, ((void)0)); BOUND(0);
    TILE_PH(31, aoff0, ((void)0));
    TILE_PH(31, aoff1, ((void)0));

    // ---- epilogue: 32x32 C/D layout col=lane&31, row=(r&3)+8*(r>>2)+4*(lane>>5) ----
    #pragma unroll
    for (int im = 0; im < 4; ++im) {
        int rxv[16];
        #pragma unroll
        for (int r = 0; r < 16; ++r)
            rxv[r] = rx[bm0 + wr * 128 + im * 32 + (r & 3) + 8 * (r >> 2) + 4 * lk];
        #pragma unroll
        for (int jn = 0; jn < 2; ++jn) {
            const int col = bn0 + wc * 64 + jn * 32 + l31;
            const float gg = g[col];
            const float ff = F0[col];
            const int   aa = al[col];
            #pragma unroll
            for (int r = 0; r < 16; ++r) {
                const int grow = bm0 + wr * 128 + im * 32 + (r & 3) + 8 * (r >> 2) + 4 * lk;
                const int tv = acc[im][jn][r] + aa * rxv[r];
                C[(size_t)grow * N_DIM + col] = fmaf(gg, (float)tv, ff);
            }
        }
    }
#undef TILE_PH
#undef STAGE_A
#undef STAGE_B
#undef BOUND
}

// ---------------- launch ----------------

extern "C" void kernel_launch(void* const* d_in, const int* in_sizes, int n_in,
                              void* d_out, int out_size, void* d_ws, size_t ws_size,
                              hipStream_t stream) {
    const float* x        = (const float*)d_in[0];
    const float* a_scale  = (const float*)d_in[1];
    const int*   a_zp     = (const int*)d_in[2];
    const int*   weight_q = (const int*)d_in[3];
    const float* w_scale  = (const float*)d_in[4];
    const int*   w_zp     = (const int*)d_in[5];
    const float* bias     = (const float*)d_in[6];
    float*       out      = (float*)d_out;

    char* ws = (char*)d_ws;
    signed char* xc = (signed char*)(ws + XC_OFF);
    signed char* wc = (signed char*)(ws + WC_OFF);
    int*   rx = (int*)(ws + RX_OFF);
    int*   al = (int*)(ws + AL_OFF);
    float* g  = (float*)(ws + G_OFF);
    float* F0 = (float*)(ws + F0_OFF);

    prep_x_kernel<<<M_DIM, 256, 0, stream>>>((const float4*)x, xc, rx, a_scale, a_zp);
    prep_w_kernel<<<N_DIM, 256, 0, stream>>>((const int4*)weight_q, wc, al, g, F0,
                                             a_scale, a_zp, w_scale, w_zp, bias);

    gemm_i8_kernel<<<512, 512, 131072, stream>>>(xc, wc, rx, al, g, F0, out);
}

// Round 7
// 288.618 us; speedup vs baseline: 1.2595x; 1.0008x over previous
//
#include <hip/hip_runtime.h>
#include <hip/hip_bf16.h>

// Problem constants: B=2, S=2048, DIN=2048, DOUT=8192
#define M_DIM 4096
#define K_DIM 2048
#define N_DIM 8192

typedef int   int32x4  __attribute__((ext_vector_type(4)));
typedef int   int32x16 __attribute__((ext_vector_type(16)));

// ---------------- workspace layout (bytes) ----------------
#define XC_OFF 0
#define WC_OFF 8388608UL
#define RX_OFF 25165824UL
#define AL_OFF 25182208UL
#define G_OFF  25214976UL
#define F0_OFF 25247744UL

__device__ __forceinline__ int pack4(int a, int b, int c, int d) {
    return (a & 255) | ((b & 255) << 8) | ((c & 255) << 16) | ((d & 255) << 24);
}

// ---------------- prep: x -> x' = clip(round(x/s)+z,0,255)-128, plus row-sum rx ----------------
__global__ __launch_bounds__(256) void prep_x_kernel(
    const float4* __restrict__ x, signed char* __restrict__ xc, int* __restrict__ rx,
    const float* __restrict__ a_scale, const int* __restrict__ a_zp)
{
    const int row = blockIdx.x;
    const int tid = threadIdx.x;
    const float s = a_scale[0];
    const float z = (float)a_zp[0];
    int sum = 0;
    int* xci = (int*)(xc + (size_t)row * K_DIM);
    const float4* xr = x + (size_t)row * (K_DIM / 4);
    #pragma unroll
    for (int it = 0; it < 2; ++it) {
        int qi = tid + it * 256;
        float4 v = xr[qi];
        int q0 = (int)(fminf(fmaxf(roundf(v.x / s) + z, 0.f), 255.f)) - 128;
        int q1 = (int)(fminf(fmaxf(roundf(v.y / s) + z, 0.f), 255.f)) - 128;
        int q2 = (int)(fminf(fmaxf(roundf(v.z / s) + z, 0.f), 255.f)) - 128;
        int q3 = (int)(fminf(fmaxf(roundf(v.w / s) + z, 0.f), 255.f)) - 128;
        sum += q0 + q1 + q2 + q3;
        xci[qi] = pack4(q0, q1, q2, q3);
    }
    #pragma unroll
    for (int off = 32; off > 0; off >>= 1) sum += __shfl_down(sum, off);
    __shared__ int wsum[4];
    if ((tid & 63) == 0) wsum[tid >> 6] = sum;
    __syncthreads();
    if (tid == 0) rx[row] = wsum[0] + wsum[1] + wsum[2] + wsum[3];
}

// ---------------- prep: w -> w' = w_q-128, plus per-channel alpha/g/F0 ----------------
__global__ __launch_bounds__(256) void prep_w_kernel(
    const int4* __restrict__ wq, signed char* __restrict__ wc,
    int* __restrict__ al, float* __restrict__ g, float* __restrict__ F0,
    const float* __restrict__ a_scale, const int* __restrict__ a_zp,
    const float* __restrict__ w_scale, const int* __restrict__ w_zp,
    const float* __restrict__ bias)
{
    const int o   = blockIdx.x;
    const int tid = threadIdx.x;
    int sum = 0;
    int* wci = (int*)(wc + (size_t)o * K_DIM);
    const int4* wr = wq + (size_t)o * (K_DIM / 4);
    #pragma unroll
    for (int it = 0; it < 2; ++it) {
        int qi = tid + it * 256;
        int4 v = wr[qi];
        int q0 = v.x - 128, q1 = v.y - 128, q2 = v.z - 128, q3 = v.w - 128;
        sum += q0 + q1 + q2 + q3;
        wci[qi] = pack4(q0, q1, q2, q3);
    }
    #pragma unroll
    for (int off = 32; off > 0; off >>= 1) sum += __shfl_down(sum, off);
    __shared__ int wsum[4];
    if ((tid & 63) == 0) wsum[tid >> 6] = sum;
    __syncthreads();
    if (tid == 0) {
        int rw    = wsum[0] + wsum[1] + wsum[2] + wsum[3];
        int alpha = 128 - w_zp[o];
        int beta  = 128 - a_zp[0];
        int C0    = beta * (rw + K_DIM * alpha);
        float gg  = a_scale[0] * w_scale[o];
        al[o] = alpha;
        g[o]  = gg;
        F0[o] = gg * (float)C0 + bias[o];
    }
}

// ---------------- GEMM: 256x256, BK=64B, 4 LDS buffers, 1 barrier + counted vmcnt per tile ----
// LDS tile buffer = [128 lds-rows][128 B]; lds-row r holds tile-rows {2r, 2r+1} (64 B each).
// 16B chunk c_lds at (r, c_lds) holds global chunk c_g = c_lds ^ (r&7).
// Ledger (per-wave, 4 glds16 per STAGE):
//   prologue: groups {0,1,2} issued (12); vmcnt(8) -> group 0 done; s_barrier -> ALL waves'
//     group-0 slices visible (vmcnt is per-wave; the barrier is what extends it block-wide).
//   tile u: reads(u) [guarded by tile u-1's vmcnt(4)+barrier -> group u visible];
//     vmcnt(4) -> group u+1 done (outstanding {u+1,u+2}=8 -> 4);
//     s_barrier (+ sched_barrier(0): s_barrier is not a memory-scheduling fence; prevents
//     STAGE hoisting above it, which would race slow waves' in-flight reads(u-1));
//     STAGE(u+3) -> buf (u-1)&3, whose reads completed before all waves arrived at barrier(u);
//     16-MFMA cluster (lgkm waits auto-inserted; cluster completion precedes barrier(u+1)).

__device__ __forceinline__ void glds16(const void* gptr, void* lptr) {
    __builtin_amdgcn_global_load_lds(
        (const __attribute__((address_space(1))) void*)gptr,
        (__attribute__((address_space(3))) void*)lptr, 16, 0, 0);
}

// out[m,o] = g[o]*float(sum_k x'[m,k]*w'[o,k] + al[o]*rx[m]) + F0[o]
__global__ __launch_bounds__(512) void gemm_i8_kernel(
    const signed char* __restrict__ A,
    const signed char* __restrict__ Bw,
    const int*   __restrict__ rx,
    const int*   __restrict__ al,
    const float* __restrict__ g,
    const float* __restrict__ F0,
    float* __restrict__ C)
{
    extern __shared__ signed char lds[];     // 131072 B: A bufs [0,64K), B bufs [64K,128K)
    signed char* ldsA = lds;
    signed char* ldsB = lds + 65536;

    const int tid  = threadIdx.x;
    const int lane = tid & 63;
    const int wave = tid >> 6;      // 8 waves
    const int wr   = wave >> 2;     // 0..1  (M)
    const int wc   = wave & 3;      // 0..3  (N)
    const int l31  = lane & 31;
    const int lk   = lane >> 5;     // 0..1

    // XCD-aware bijective swizzle: XCD x = bid&7 gets 4 m-tiles x 16 n-tiles.
    const int bid = blockIdx.x;
    const int x7  = bid & 7;
    const int lcl = bid >> 3;
    const int bm0 = ((x7 & 3) * 4 + (lcl & 3)) * 256;
    const int bn0 = ((x7 >> 2) * 16 + (lcl >> 2)) * 256;

    // ---- staging: thread tid -> lds-row slr = tid>>3, chunk c_lds = tid&7 ----
    const int slr = tid >> 3;
    const int cg  = (tid & 7) ^ (slr & 7);
    const int sp  = cg >> 2;
    const int skc = cg & 3;
    const signed char* srcA0 = A  + (size_t)(bm0 + 2 * slr + sp) * K_DIM + skc * 16;
    const signed char* srcA1 = srcA0 + (size_t)128 * K_DIM;
    const signed char* srcB0 = Bw + (size_t)(bn0 + 2 * slr + sp) * K_DIM + skc * 16;
    const signed char* srcB1 = srcB0 + (size_t)128 * K_DIM;
    signed char* dstA0 = ldsA + tid * 16;
    signed char* dstB0 = ldsB + tid * 16;

#define STAGE(s) { const int kof = (s) * 64; const int bo = ((s) & 3) * 16384; \
    glds16(srcA0 + kof, dstA0 + bo); glds16(srcA1 + kof, dstA0 + bo + 8192); \
    glds16(srcB0 + kof, dstB0 + bo); glds16(srcB1 + kof, dstB0 + bo + 8192); }

    // ---- fragment read addressing (paired-row XOR layout) ----
    const int q  = l31 >> 1;
    const int e  = q & 7;
    const int pp = l31 & 1;
    int arowb[4], browb[2];
    #pragma unroll
    for (int im = 0; im < 4; ++im) arowb[im] = (wr * 64 + im * 16 + q) * 128;
    #pragma unroll
    for (int jn = 0; jn < 2; ++jn) browb[jn] = (wc * 32 + jn * 16 + q) * 128;
    const int aoff0 = ((pp * 4 + lk) ^ e) * 16;   // ks=0
    const int aoff1 = aoff0 ^ 32;                 // ks=1

    int32x16 acc[4][2];
    #pragma unroll
    for (int im = 0; im < 4; ++im)
        #pragma unroll
        for (int jn = 0; jn < 2; ++jn)
            acc[im][jn] = (int32x16)(0);

// One K-tile: 12 reads -> vmcnt(N)+barrier(+sched fence) -> optional stage -> 16 MFMA cluster.
#define TILE(T, VMC, STAGE_STMT) { \
    const int bo_ = ((T) & 3) * 16384; \
    int32x4 a0[4], b0[2], a1[4], b1[2]; \
    _Pragma("unroll") for (int im = 0; im < 4; ++im) \
        a0[im] = *(const int32x4*)(ldsA + bo_ + arowb[im] + aoff0); \
    _Pragma("unroll") for (int jn = 0; jn < 2; ++jn) \
        b0[jn] = *(const int32x4*)(ldsB + bo_ + browb[jn] + aoff0); \
    _Pragma("unroll") for (int im = 0; im < 4; ++im) \
        a1[im] = *(const int32x4*)(ldsA + bo_ + arowb[im] + aoff1); \
    _Pragma("unroll") for (int jn = 0; jn < 2; ++jn) \
        b1[jn] = *(const int32x4*)(ldsB + bo_ + browb[jn] + aoff1); \
    asm volatile("s_waitcnt vmcnt(" #VMC ")" ::: "memory"); \
    __builtin_amdgcn_s_barrier(); \
    __builtin_amdgcn_sched_barrier(0); \
    STAGE_STMT; \
    __builtin_amdgcn_s_setprio(1); \
    _Pragma("unroll") for (int im = 0; im < 4; ++im) \
        _Pragma("unroll") for (int jn = 0; jn < 2; ++jn) \
            acc[im][jn] = __builtin_amdgcn_mfma_i32_32x32x32_i8(a0[im], b0[jn], acc[im][jn], 0, 0, 0); \
    _Pragma("unroll") for (int im = 0; im < 4; ++im) \
        _Pragma("unroll") for (int jn = 0; jn < 2; ++jn) \
            acc[im][jn] = __builtin_amdgcn_mfma_i32_32x32x32_i8(a1[im], b1[jn], acc[im][jn], 0, 0, 0); \
    __builtin_amdgcn_s_setprio(0); \
}

    // prologue: stage tiles 0,1,2; vmcnt(8) -> own group-0 slice done;
    // s_barrier -> ALL waves' group-0 slices visible (this barrier was the round-6 bug).
    STAGE(0); STAGE(1); STAGE(2);
    asm volatile("s_waitcnt vmcnt(8)" ::: "memory");
    __builtin_amdgcn_s_barrier();

    // main loop: tiles 0..28 stage t+3; vmcnt(4) ensures group t+1 arrived.
    #pragma unroll 1
    for (int t = 0; t < 29; ++t) {
        TILE(t, 4, STAGE(t + 3));
    }
    TILE(29, 4, ((void)0));     // ensures group 30 (outstanding {30,31} -> leave 4)
    TILE(30, 0, ((void)0));     // ensures group 31
    TILE(31, 0, ((void)0));

    // ---- epilogue: 32x32 C/D layout col=lane&31, row=(r&3)+8*(r>>2)+4*(lane>>5) ----
    #pragma unroll
    for (int im = 0; im < 4; ++im) {
        int rxv[16];
        #pragma unroll
        for (int r = 0; r < 16; ++r)
            rxv[r] = rx[bm0 + wr * 128 + im * 32 + (r & 3) + 8 * (r >> 2) + 4 * lk];
        #pragma unroll
        for (int jn = 0; jn < 2; ++jn) {
            const int col = bn0 + wc * 64 + jn * 32 + l31;
            const float gg = g[col];
            const float ff = F0[col];
            const int   aa = al[col];
            #pragma unroll
            for (int r = 0; r < 16; ++r) {
                const int grow = bm0 + wr * 128 + im * 32 + (r & 3) + 8 * (r >> 2) + 4 * lk;
                const int tv = acc[im][jn][r] + aa * rxv[r];
                C[(size_t)grow * N_DIM + col] = fmaf(gg, (float)tv, ff);
            }
        }
    }
#undef TILE
#undef STAGE
}

// ---------------- launch ----------------

extern "C" void kernel_launch(void* const* d_in, const int* in_sizes, int n_in,
                              void* d_out, int out_size, void* d_ws, size_t ws_size,
                              hipStream_t stream) {
    const float* x        = (const float*)d_in[0];
    const float* a_scale  = (const float*)d_in[1];
    const int*   a_zp     = (const int*)d_in[2];
    const int*   weight_q = (const int*)d_in[3];
    const float* w_scale  = (const float*)d_in[4];
    const int*   w_zp     = (const int*)d_in[5];
    const float* bias     = (const float*)d_in[6];
    float*       out      = (float*)d_out;

    char* ws = (char*)d_ws;
    signed char* xc = (signed char*)(ws + XC_OFF);
    signed char* wc = (signed char*)(ws + WC_OFF);
    int*   rx = (int*)(ws + RX_OFF);
    int*   al = (int*)(ws + AL_OFF);
    float* g  = (float*)(ws + G_OFF);
    float* F0 = (float*)(ws + F0_OFF);

    prep_x_kernel<<<M_DIM, 256, 0, stream>>>((const float4*)x, xc, rx, a_scale, a_zp);
    prep_w_kernel<<<N_DIM, 256, 0, stream>>>((const int4*)weight_q, wc, al, g, F0,
                                             a_scale, a_zp, w_scale, w_zp, bias);

    gemm_i8_kernel<<<512, 512, 131072, stream>>>(xc, wc, rx, al, g, F0, out);
}